// Round 1
// baseline (417.504 us; speedup 1.0000x reference)
//
#include <hip/hip_runtime.h>
#include <stdint.h>

typedef float f32x4 __attribute__((ext_vector_type(4)));
typedef long i64;

#define HID 768
#define UNITS 768
#define BM 64               /* rows per GEMM block */
#define BN 384              /* cols per GEMM block (2 n-halves) */
#define LDS_STRIDE 776      /* 768 + 8 pad: <=2-way LDS aliasing on ds_read_b64 */
#define NFRAG 6             /* n-frags per wave: 6*16 = 96 cols */
#define MFRAG 4             /* m-frags per wave: 4*16 = 64 rows */
#define KK_STEPS 24         /* 768 / 32 */
#define NPKT (48 * 24)      /* B n-frag tiles * k-steps */

// ---------- fp8 e4m3fn conversion (RNE, saturating) ----------
__device__ __forceinline__ uint8_t f32_to_e4m3_sw(float x) {
    uint32_t u;
    __builtin_memcpy(&u, &x, 4);
    uint32_t sign = (u >> 24) & 0x80u;
    uint32_t a = u & 0x7fffffffu;
    if (a > 0x43e00000u) return (uint8_t)(sign | 0x7e);      // >448: saturate
    if (a < 0x3c800000u) {                                   // < 2^-6: subnormal
        float s;
        __builtin_memcpy(&s, &a, 4);
        int q = (int)rintf(s * 512.0f);
        return (uint8_t)(sign | (uint32_t)q);
    }
    uint32_t e = a >> 23;
    uint32_t m = a & 0x7fffffu;
    uint32_t mant = m >> 20;
    uint32_t rest = m & 0xfffffu;
    mant += (rest > 0x80000u) || (rest == 0x80000u && (mant & 1u));
    uint32_t te = e - 127u + 7u;
    if (mant == 8u) { mant = 0u; te += 1u; }
    return (uint8_t)(sign | (te << 3) | mant);
}

__device__ __forceinline__ uint32_t pack4_e4m3(float a, float b, float c, float d) {
#if __has_builtin(__builtin_amdgcn_cvt_pk_fp8_f32)
    int v = 0;
    v = __builtin_amdgcn_cvt_pk_fp8_f32(a, b, v, false);     // bytes 0,1
    v = __builtin_amdgcn_cvt_pk_fp8_f32(c, d, v, true);      // bytes 2,3
    return (uint32_t)v;
#else
    return (uint32_t)f32_to_e4m3_sw(a) | ((uint32_t)f32_to_e4m3_sw(b) << 8) |
           ((uint32_t)f32_to_e4m3_sw(c) << 16) | ((uint32_t)f32_to_e4m3_sw(d) << 24);
#endif
}

// ---------- kernel 1: quantize + frag-pack weights ----------
// Packet p = fn*KK_STEPS + kk. Byte offset p*512 + lane*8 holds
// B[k][n] for n = fn*16 + (lane&15), k = kk*32 + (lane>>4)*8 + j  (j = byte 0..7)
__global__ void pack_b_kernel(const float* __restrict__ K, uint8_t* __restrict__ Bp) {
    const int lane = threadIdx.x & 63;
    const int wid = (int)((blockIdx.x * blockDim.x + threadIdx.x) >> 6);
    if (wid >= NPKT) return;
    const int fn = wid / KK_STEPS, kk = wid % KK_STEPS;
    const int n = fn * 16 + (lane & 15);
    const int k0 = kk * 32 + (lane >> 4) * 8;
    float v[8];
#pragma unroll
    for (int j = 0; j < 8; ++j) v[j] = K[(size_t)(k0 + j) * UNITS + n];
    uint2 pr;
    pr.x = pack4_e4m3(v[0], v[1], v[2], v[3]);
    pr.y = pack4_e4m3(v[4], v[5], v[6], v[7]);
    *(uint2*)(Bp + ((size_t)wid << 9) + (size_t)lane * 8) = pr;
}

// ---------- kernel 2a: LayerNorm + fp8 quantize + frag-pack activations ----------
// Same packet layout as B: packet p = frag*KK_STEPS + kk (frag = row/16),
// byte p*512 + lane*8 holds A[row = frag*16 + (lane&15)][k = kk*32 + (lane>>4)*8 + j].
// 16 rows per block (one m-frag), 4 rows per wave, fully unrolled for load ILP.
__global__ __launch_bounds__(256, 4)
void ln_pack_a(const float* __restrict__ x,
               const float* __restrict__ gamma,
               const float* __restrict__ beta,
               uint8_t* __restrict__ Ap) {
    __shared__ uint8_t Alds[16 * LDS_STRIDE];   // 12416 B -> LDS-occupancy >= 12 blocks/CU
    const int tid = threadIdx.x;
    const int lane = tid & 63;
    const int wave = tid >> 6;
    const int frag = (int)blockIdx.x;
    const int row0 = frag * 16 + wave * 4;

    // gamma/beta loaded once, broadcast across the 4 rows this wave handles
    float4 g[3], bb[3];
#pragma unroll
    for (int i = 0; i < 3; ++i) {
        g[i]  = ((const float4*)gamma)[i * 64 + lane];
        bb[i] = ((const float4*)beta )[i * 64 + lane];
    }

    // 12 independent float4 loads in flight before any reduce
    float4 v[4][3];
    float s[4], s2[4];
#pragma unroll
    for (int r = 0; r < 4; ++r) {
        const float4* xr = (const float4*)(x + (size_t)(row0 + r) * HID);
        s[r] = 0.f; s2[r] = 0.f;
#pragma unroll
        for (int i = 0; i < 3; ++i) {
            const float4 t = xr[i * 64 + lane];
            v[r][i] = t;
            s[r]  += t.x + t.y + t.z + t.w;
            s2[r] += t.x * t.x + t.y * t.y + t.z * t.z + t.w * t.w;
        }
    }
    // 4 independent butterfly chains interleaved (ILP over the shuffle latency)
#pragma unroll
    for (int off = 32; off; off >>= 1) {
#pragma unroll
        for (int r = 0; r < 4; ++r) {
            s[r]  += __shfl_xor(s[r], off);
            s2[r] += __shfl_xor(s2[r], off);
        }
    }
#pragma unroll
    for (int r = 0; r < 4; ++r) {
        const float mu = s[r] * (1.0f / HID);
        const float var = fmaxf(s2[r] * (1.0f / HID) - mu * mu, 0.0f);
        const float rs = rsqrtf(var + 1e-5f);
#pragma unroll
        for (int i = 0; i < 3; ++i) {
            const int c4 = i * 64 + lane;
            const float y0 = (v[r][i].x - mu) * rs * g[i].x + bb[i].x;
            const float y1 = (v[r][i].y - mu) * rs * g[i].y + bb[i].y;
            const float y2 = (v[r][i].z - mu) * rs * g[i].z + bb[i].z;
            const float y3 = (v[r][i].w - mu) * rs * g[i].w + bb[i].w;
            *(uint32_t*)&Alds[(wave * 4 + r) * LDS_STRIDE + c4 * 4] = pack4_e4m3(y0, y1, y2, y3);
        }
    }
    __syncthreads();

    // repack LDS -> global fragment packets; 512 B fully-coalesced store per wave
    const int nl = lane & 15, quad = lane >> 4;
#pragma unroll
    for (int t = 0; t < KK_STEPS / 4; ++t) {
        const int kk = wave * (KK_STEPS / 4) + t;
        const i64 val = *(const i64*)&Alds[nl * LDS_STRIDE + quad * 8 + kk * 32];
        ((i64*)Ap)[((size_t)frag * KK_STEPS + kk) * 64 + lane] = val;
    }
}

// ---------- kernel 2b: barrier-free LDS-free fp8 register GEMM + bias ----------
__global__ __launch_bounds__(256, 3)
void gemm_packed(const uint8_t* __restrict__ Ap,
                 const uint8_t* __restrict__ Bp,
                 const float* __restrict__ bias,
                 float* __restrict__ out) {
    const int tid = threadIdx.x;
    const int lane = tid & 63;
    const int wave = tid >> 6;
    const int bid = (int)blockIdx.x;
    const int ny = bid & 1;            // n-half fastest: ny pair shares the A m-tile in L2/L3
    const int mt = bid >> 1;
    const int row0 = mt * BM;
    const int nl = lane & 15, quad = lane >> 4;

    f32x4 acc[MFRAG][NFRAG];
#pragma unroll
    for (int mf = 0; mf < MFRAG; ++mf)
#pragma unroll
        for (int f = 0; f < NFRAG; ++f) acc[mf][f] = (f32x4){0.f, 0.f, 0.f, 0.f};

    const i64* Aq = (const i64*)Ap;
    const i64* Bq = (const i64*)Bp;
    const int fn0 = ny * 24 + wave * NFRAG;
    const size_t abase = (size_t)(mt * MFRAG) * KK_STEPS * 64 + lane;

    // double-buffer one k-step ahead for both operands
    i64 acur[MFRAG], bcur[NFRAG];
#pragma unroll
    for (int mf = 0; mf < MFRAG; ++mf)
        acur[mf] = Aq[abase + (size_t)mf * KK_STEPS * 64];
#pragma unroll
    for (int f = 0; f < NFRAG; ++f)
        bcur[f] = Bq[(size_t)((fn0 + f) * KK_STEPS) * 64 + lane];

#pragma unroll 2
    for (int kk = 0; kk < KK_STEPS; ++kk) {
        const int kn = (kk + 1 < KK_STEPS) ? kk + 1 : kk;
        i64 anxt[MFRAG], bnxt[NFRAG];
#pragma unroll
        for (int mf = 0; mf < MFRAG; ++mf)
            anxt[mf] = Aq[abase + ((size_t)mf * KK_STEPS + kn) * 64];
#pragma unroll
        for (int f = 0; f < NFRAG; ++f)
            bnxt[f] = Bq[(size_t)((fn0 + f) * KK_STEPS + kn) * 64 + lane];

#pragma unroll
        for (int f = 0; f < NFRAG; ++f)
#pragma unroll
            for (int mf = 0; mf < MFRAG; ++mf)
                acc[mf][f] = __builtin_amdgcn_mfma_f32_16x16x32_fp8_fp8(acur[mf], bcur[f], acc[mf][f], 0, 0, 0);

#pragma unroll
        for (int mf = 0; mf < MFRAG; ++mf) acur[mf] = anxt[mf];
#pragma unroll
        for (int f = 0; f < NFRAG; ++f) bcur[f] = bnxt[f];
    }

    // ---- Epilogue: + bias, store fp32 (64 B per 16-lane quad, coalesced) ----
#pragma unroll
    for (int f = 0; f < NFRAG; ++f) {
        const int col = ny * BN + wave * 96 + f * 16 + nl;
        const float bv = bias[col];
#pragma unroll
        for (int mf = 0; mf < MFRAG; ++mf) {
            const int row = row0 + mf * 16 + quad * 4;
            float* o = out + (size_t)row * UNITS + col;
            o[0 * UNITS] = acc[mf][f][0] + bv;
            o[1 * UNITS] = acc[mf][f][1] + bv;
            o[2 * UNITS] = acc[mf][f][2] + bv;
            o[3 * UNITS] = acc[mf][f][3] + bv;
        }
    }
}

// ---------- fallback: previous fused kernel (used only if workspace too small) ----------
__global__ __launch_bounds__(256, 3)
void fused_ln_gemm(const float* __restrict__ x,
                   const float* __restrict__ gamma,
                   const float* __restrict__ beta,
                   const uint8_t* __restrict__ Bp,
                   const float* __restrict__ bias,
                   float* __restrict__ out) {
    __shared__ uint8_t Alds[BM * LDS_STRIDE];
    const int tid = threadIdx.x;
    const int lane = tid & 63;
    const int wave = tid >> 6;
    const int bid = (int)blockIdx.x;
    const int ny = bid & 1;
    const int mt = bid >> 1;
    const int row0 = mt * BM;

    for (int rr = 0; rr < BM / 4; ++rr) {
        const int row = wave * (BM / 4) + rr;
        const float4* xr = (const float4*)(x + (size_t)(row0 + row) * HID);
        float4 v[3];
        float s = 0.f, s2 = 0.f;
#pragma unroll
        for (int i = 0; i < 3; ++i) {
            v[i] = xr[i * 64 + lane];
            s  += v[i].x + v[i].y + v[i].z + v[i].w;
            s2 += v[i].x * v[i].x + v[i].y * v[i].y + v[i].z * v[i].z + v[i].w * v[i].w;
        }
#pragma unroll
        for (int off = 32; off; off >>= 1) {
            s  += __shfl_xor(s, off);
            s2 += __shfl_xor(s2, off);
        }
        const float mu = s * (1.0f / HID);
        const float var = fmaxf(s2 * (1.0f / HID) - mu * mu, 0.0f);
        const float rs = rsqrtf(var + 1e-5f);
#pragma unroll
        for (int i = 0; i < 3; ++i) {
            const int c4 = i * 64 + lane;
            const float4 g  = ((const float4*)gamma)[c4];
            const float4 bb = ((const float4*)beta)[c4];
            const float y0 = (v[i].x - mu) * rs * g.x + bb.x;
            const float y1 = (v[i].y - mu) * rs * g.y + bb.y;
            const float y2 = (v[i].z - mu) * rs * g.z + bb.z;
            const float y3 = (v[i].w - mu) * rs * g.w + bb.w;
            *(uint32_t*)&Alds[row * LDS_STRIDE + c4 * 4] = pack4_e4m3(y0, y1, y2, y3);
        }
    }
    __syncthreads();

    const int nl = lane & 15, quad = lane >> 4;
    f32x4 acc[MFRAG][NFRAG];
#pragma unroll
    for (int mf = 0; mf < MFRAG; ++mf)
#pragma unroll
        for (int f = 0; f < NFRAG; ++f) acc[mf][f] = (f32x4){0.f, 0.f, 0.f, 0.f};

    const uint8_t* ap[MFRAG];
#pragma unroll
    for (int mf = 0; mf < MFRAG; ++mf)
        ap[mf] = &Alds[(mf * 16 + nl) * LDS_STRIDE + quad * 8];

    const i64* Bq = (const i64*)Bp;
    const int fn0 = ny * 24 + wave * NFRAG;

    i64 bcur[NFRAG];
#pragma unroll
    for (int f = 0; f < NFRAG; ++f)
        bcur[f] = Bq[(size_t)((fn0 + f) * KK_STEPS) * 64 + lane];

#pragma unroll 4
    for (int kk = 0; kk < KK_STEPS; ++kk) {
        const int kn = (kk + 1 < KK_STEPS) ? kk + 1 : kk;
        i64 bnxt[NFRAG];
#pragma unroll
        for (int f = 0; f < NFRAG; ++f)
            bnxt[f] = Bq[(size_t)((fn0 + f) * KK_STEPS + kn) * 64 + lane];

        i64 a[MFRAG];
#pragma unroll
        for (int mf = 0; mf < MFRAG; ++mf)
            a[mf] = *(const i64*)(ap[mf] + kk * 32);

#pragma unroll
        for (int f = 0; f < NFRAG; ++f)
#pragma unroll
            for (int mf = 0; mf < MFRAG; ++mf)
                acc[mf][f] = __builtin_amdgcn_mfma_f32_16x16x32_fp8_fp8(a[mf], bcur[f], acc[mf][f], 0, 0, 0);

#pragma unroll
        for (int f = 0; f < NFRAG; ++f) bcur[f] = bnxt[f];
    }

#pragma unroll
    for (int f = 0; f < NFRAG; ++f) {
        const int col = ny * BN + wave * 96 + f * 16 + nl;
        const float bv = bias[col];
#pragma unroll
        for (int mf = 0; mf < MFRAG; ++mf) {
            const int row = row0 + mf * 16 + quad * 4;
            float* o = out + (size_t)row * UNITS + col;
            o[0 * UNITS] = acc[mf][f][0] + bv;
            o[1 * UNITS] = acc[mf][f][1] + bv;
            o[2 * UNITS] = acc[mf][f][2] + bv;
            o[3 * UNITS] = acc[mf][f][3] + bv;
        }
    }
}

extern "C" void kernel_launch(void* const* d_in, const int* in_sizes, int n_in,
                              void* d_out, int out_size, void* d_ws, size_t ws_size,
                              hipStream_t stream) {
    const float* x     = (const float*)d_in[0];
    const float* gamma = (const float*)d_in[1];
    const float* beta  = (const float*)d_in[2];
    const float* kern  = (const float*)d_in[3];
    const float* bias  = (const float*)d_in[4];
    float* out = (float*)d_out;
    const int tokens = in_sizes[0] / HID;

    uint8_t* Bp = (uint8_t*)d_ws;                    // 48*24*512 = 589824 B
    const size_t bp_bytes = (size_t)NPKT * 512;
    const size_t ap_bytes = (size_t)tokens * HID;    // fp8 activations, 50.3 MB

    hipLaunchKernelGGL(pack_b_kernel, dim3((NPKT * 64 + 255) / 256), dim3(256), 0, stream,
                       kern, Bp);

    if (ws_size >= bp_bytes + ap_bytes) {
        uint8_t* Ap = Bp + bp_bytes;
        hipLaunchKernelGGL(ln_pack_a, dim3(tokens / 16), dim3(256), 0, stream,
                           x, gamma, beta, Ap);
        hipLaunchKernelGGL(gemm_packed, dim3((tokens / BM) * 2), dim3(256), 0, stream,
                           Ap, Bp, bias, out);
    } else {
        // workspace too small for the split path: previous proven fused kernel
        hipLaunchKernelGGL(fused_ln_gemm, dim3((tokens / BM) * 2), dim3(256), 0, stream,
                           x, gamma, beta, Bp, bias, out);
    }
}

// Round 2
// 412.993 us; speedup vs baseline: 1.0109x; 1.0109x over previous
//
#include <hip/hip_runtime.h>
#include <stdint.h>

typedef float f32x4 __attribute__((ext_vector_type(4)));
typedef long i64;

#define HID 768
#define UNITS 768
#define BM 64               /* rows per GEMM block */
#define BN 384              /* cols per GEMM block (2 n-halves) */
#define LDS_STRIDE 776      /* 768 + 8 pad: <=2-way LDS aliasing on ds_read_b64 */
#define NFRAG 6             /* n-frags per wave: 6*16 = 96 cols */
#define MFRAG 4             /* m-frags per wave: 4*16 = 64 rows */
#define KK_STEPS 24         /* 768 / 32 */
#define NPKT (48 * 24)      /* B n-frag tiles * k-steps */

// ---------- fp8 e4m3fn conversion (RNE, saturating) ----------
__device__ __forceinline__ uint8_t f32_to_e4m3_sw(float x) {
    uint32_t u;
    __builtin_memcpy(&u, &x, 4);
    uint32_t sign = (u >> 24) & 0x80u;
    uint32_t a = u & 0x7fffffffu;
    if (a > 0x43e00000u) return (uint8_t)(sign | 0x7e);      // >448: saturate
    if (a < 0x3c800000u) {                                   // < 2^-6: subnormal
        float s;
        __builtin_memcpy(&s, &a, 4);
        int q = (int)rintf(s * 512.0f);
        return (uint8_t)(sign | (uint32_t)q);
    }
    uint32_t e = a >> 23;
    uint32_t m = a & 0x7fffffu;
    uint32_t mant = m >> 20;
    uint32_t rest = m & 0xfffffu;
    mant += (rest > 0x80000u) || (rest == 0x80000u && (mant & 1u));
    uint32_t te = e - 127u + 7u;
    if (mant == 8u) { mant = 0u; te += 1u; }
    return (uint8_t)(sign | (te << 3) | mant);
}

__device__ __forceinline__ uint32_t pack4_e4m3(float a, float b, float c, float d) {
#if __has_builtin(__builtin_amdgcn_cvt_pk_fp8_f32)
    int v = 0;
    v = __builtin_amdgcn_cvt_pk_fp8_f32(a, b, v, false);     // bytes 0,1
    v = __builtin_amdgcn_cvt_pk_fp8_f32(c, d, v, true);      // bytes 2,3
    return (uint32_t)v;
#else
    return (uint32_t)f32_to_e4m3_sw(a) | ((uint32_t)f32_to_e4m3_sw(b) << 8) |
           ((uint32_t)f32_to_e4m3_sw(c) << 16) | ((uint32_t)f32_to_e4m3_sw(d) << 24);
#endif
}

// ---------- kernel 1: quantize + frag-pack weights ----------
// Packet p = fn*KK_STEPS + kk. Byte offset p*512 + lane*8 holds
// B[k][n] for n = fn*16 + (lane&15), k = kk*32 + (lane>>4)*8 + j  (j = byte 0..7)
__global__ void pack_b_kernel(const float* __restrict__ K, uint8_t* __restrict__ Bp) {
    const int lane = threadIdx.x & 63;
    const int wid = (int)((blockIdx.x * blockDim.x + threadIdx.x) >> 6);
    if (wid >= NPKT) return;
    const int fn = wid / KK_STEPS, kk = wid % KK_STEPS;
    const int n = fn * 16 + (lane & 15);
    const int k0 = kk * 32 + (lane >> 4) * 8;
    float v[8];
#pragma unroll
    for (int j = 0; j < 8; ++j) v[j] = K[(size_t)(k0 + j) * UNITS + n];
    uint2 pr;
    pr.x = pack4_e4m3(v[0], v[1], v[2], v[3]);
    pr.y = pack4_e4m3(v[4], v[5], v[6], v[7]);
    *(uint2*)(Bp + ((size_t)wid << 9) + (size_t)lane * 8) = pr;
}

// ---------- kernel 2a: LayerNorm + fp8 quantize + frag-pack activations ----------
// Same packet layout as B: packet p = frag*KK_STEPS + kk (frag = row/16),
// byte p*512 + lane*8 holds A[row = frag*16 + (lane&15)][k = kk*32 + (lane>>4)*8 + j].
__global__ __launch_bounds__(256, 4)
void ln_pack_a(const float* __restrict__ x,
               const float* __restrict__ gamma,
               const float* __restrict__ beta,
               uint8_t* __restrict__ Ap) {
    __shared__ uint8_t Alds[16 * LDS_STRIDE];   // 12416 B
    const int tid = threadIdx.x;
    const int lane = tid & 63;
    const int wave = tid >> 6;
    const int frag = (int)blockIdx.x;
    const int row0 = frag * 16 + wave * 4;

    float4 g[3], bb[3];
#pragma unroll
    for (int i = 0; i < 3; ++i) {
        g[i]  = ((const float4*)gamma)[i * 64 + lane];
        bb[i] = ((const float4*)beta )[i * 64 + lane];
    }

    // 12 independent float4 loads in flight before any reduce
    float4 v[4][3];
    float s[4], s2[4];
#pragma unroll
    for (int r = 0; r < 4; ++r) {
        const float4* xr = (const float4*)(x + (size_t)(row0 + r) * HID);
        s[r] = 0.f; s2[r] = 0.f;
#pragma unroll
        for (int i = 0; i < 3; ++i) {
            const float4 t = xr[i * 64 + lane];
            v[r][i] = t;
            s[r]  += t.x + t.y + t.z + t.w;
            s2[r] += t.x * t.x + t.y * t.y + t.z * t.z + t.w * t.w;
        }
    }
#pragma unroll
    for (int off = 32; off; off >>= 1) {
#pragma unroll
        for (int r = 0; r < 4; ++r) {
            s[r]  += __shfl_xor(s[r], off);
            s2[r] += __shfl_xor(s2[r], off);
        }
    }
#pragma unroll
    for (int r = 0; r < 4; ++r) {
        const float mu = s[r] * (1.0f / HID);
        const float var = fmaxf(s2[r] * (1.0f / HID) - mu * mu, 0.0f);
        const float rs = rsqrtf(var + 1e-5f);
#pragma unroll
        for (int i = 0; i < 3; ++i) {
            const int c4 = i * 64 + lane;
            const float y0 = (v[r][i].x - mu) * rs * g[i].x + bb[i].x;
            const float y1 = (v[r][i].y - mu) * rs * g[i].y + bb[i].y;
            const float y2 = (v[r][i].z - mu) * rs * g[i].z + bb[i].z;
            const float y3 = (v[r][i].w - mu) * rs * g[i].w + bb[i].w;
            *(uint32_t*)&Alds[(wave * 4 + r) * LDS_STRIDE + c4 * 4] = pack4_e4m3(y0, y1, y2, y3);
        }
    }
    __syncthreads();

    // repack LDS -> global fragment packets; 512 B fully-coalesced store per wave
    const int nl = lane & 15, quad = lane >> 4;
#pragma unroll
    for (int t = 0; t < KK_STEPS / 4; ++t) {
        const int kk = wave * (KK_STEPS / 4) + t;
        const i64 val = *(const i64*)&Alds[nl * LDS_STRIDE + quad * 8 + kk * 32];
        ((i64*)Ap)[((size_t)frag * KK_STEPS + kk) * 64 + lane] = val;
    }
}

// ---------- kernel 2b: barrier-free LDS-free fp8 register GEMM + bias ----------
// Depth-3 rotating register pipeline (4-slot ring, fully unrolled -> static
// indices only). Slack for a load = 3 loop bodies (~510 cyc) > L3 latency, so
// the MFMA stream never waits on A (L3-resident) or B (L2-resident).
__global__ __launch_bounds__(256, 2)
void gemm_packed(const uint8_t* __restrict__ Ap,
                 const uint8_t* __restrict__ Bp,
                 const float* __restrict__ bias,
                 float* __restrict__ out) {
    const int tid = threadIdx.x;
    const int lane = tid & 63;
    const int wave = tid >> 6;
    const int bid = (int)blockIdx.x;
    const int ny = bid & 1;            // n-half fastest: ny pair shares the A m-tile in L2/L3
    const int mt = bid >> 1;
    const int row0 = mt * BM;
    const int nl = lane & 15, quad = lane >> 4;

    f32x4 acc[MFRAG][NFRAG];
#pragma unroll
    for (int mf = 0; mf < MFRAG; ++mf)
#pragma unroll
        for (int f = 0; f < NFRAG; ++f) acc[mf][f] = (f32x4){0.f, 0.f, 0.f, 0.f};

    const i64* Aq = (const i64*)Ap;
    const i64* Bq = (const i64*)Bp;
    const int fn0 = ny * 24 + wave * NFRAG;

    // per-fragment base pointers (k-step advances by 64 i64 = 512 B)
    const i64* aptr[MFRAG];
#pragma unroll
    for (int mf = 0; mf < MFRAG; ++mf)
        aptr[mf] = Aq + (size_t)(mt * MFRAG + mf) * KK_STEPS * 64 + lane;
    const i64* bptr[NFRAG];
#pragma unroll
    for (int f = 0; f < NFRAG; ++f)
        bptr[f] = Bq + (size_t)(fn0 + f) * KK_STEPS * 64 + lane;

#define PIPE_DEPTH 3
    i64 abuf[4][MFRAG];
    i64 bbuf[4][NFRAG];

#define LOAD_STEP(slot, ks)                                      \
    do {                                                         \
        _Pragma("unroll")                                        \
        for (int mf = 0; mf < MFRAG; ++mf)                       \
            abuf[slot][mf] = aptr[mf][(ks) * 64];                \
        _Pragma("unroll")                                        \
        for (int f = 0; f < NFRAG; ++f)                          \
            bbuf[slot][f] = bptr[f][(ks) * 64];                  \
    } while (0)

    // prologue: fill 3 pipeline slots (30 loads in flight, < vmcnt max 63)
    LOAD_STEP(0, 0);
    LOAD_STEP(1, 1);
    LOAD_STEP(2, 2);

#pragma unroll
    for (int kk = 0; kk < KK_STEPS; ++kk) {
        const int ld = kk + PIPE_DEPTH;
        if (ld < KK_STEPS) {             // compile-time after full unroll
            LOAD_STEP(ld & 3, ld);
        }
        const int cs = kk & 3;
#pragma unroll
        for (int f = 0; f < NFRAG; ++f)
#pragma unroll
            for (int mf = 0; mf < MFRAG; ++mf)
                acc[mf][f] = __builtin_amdgcn_mfma_f32_16x16x32_fp8_fp8(
                    abuf[cs][mf], bbuf[cs][f], acc[mf][f], 0, 0, 0);
    }
#undef LOAD_STEP
#undef PIPE_DEPTH

    // ---- Epilogue: + bias, nontemporal fp32 stores (don't evict L2-hot A/B) ----
#pragma unroll
    for (int f = 0; f < NFRAG; ++f) {
        const int col = ny * BN + wave * 96 + f * 16 + nl;
        const float bv = bias[col];
#pragma unroll
        for (int mf = 0; mf < MFRAG; ++mf) {
            const int row = row0 + mf * 16 + quad * 4;
            float* o = out + (size_t)row * UNITS + col;
            __builtin_nontemporal_store(acc[mf][f][0] + bv, o + 0 * UNITS);
            __builtin_nontemporal_store(acc[mf][f][1] + bv, o + 1 * UNITS);
            __builtin_nontemporal_store(acc[mf][f][2] + bv, o + 2 * UNITS);
            __builtin_nontemporal_store(acc[mf][f][3] + bv, o + 3 * UNITS);
        }
    }
}

// ---------- fallback: previous fused kernel (used only if workspace too small) ----------
__global__ __launch_bounds__(256, 3)
void fused_ln_gemm(const float* __restrict__ x,
                   const float* __restrict__ gamma,
                   const float* __restrict__ beta,
                   const uint8_t* __restrict__ Bp,
                   const float* __restrict__ bias,
                   float* __restrict__ out) {
    __shared__ uint8_t Alds[BM * LDS_STRIDE];
    const int tid = threadIdx.x;
    const int lane = tid & 63;
    const int wave = tid >> 6;
    const int bid = (int)blockIdx.x;
    const int ny = bid & 1;
    const int mt = bid >> 1;
    const int row0 = mt * BM;

    for (int rr = 0; rr < BM / 4; ++rr) {
        const int row = wave * (BM / 4) + rr;
        const float4* xr = (const float4*)(x + (size_t)(row0 + row) * HID);
        float4 v[3];
        float s = 0.f, s2 = 0.f;
#pragma unroll
        for (int i = 0; i < 3; ++i) {
            v[i] = xr[i * 64 + lane];
            s  += v[i].x + v[i].y + v[i].z + v[i].w;
            s2 += v[i].x * v[i].x + v[i].y * v[i].y + v[i].z * v[i].z + v[i].w * v[i].w;
        }
#pragma unroll
        for (int off = 32; off; off >>= 1) {
            s  += __shfl_xor(s, off);
            s2 += __shfl_xor(s2, off);
        }
        const float mu = s * (1.0f / HID);
        const float var = fmaxf(s2 * (1.0f / HID) - mu * mu, 0.0f);
        const float rs = rsqrtf(var + 1e-5f);
#pragma unroll
        for (int i = 0; i < 3; ++i) {
            const int c4 = i * 64 + lane;
            const float4 g  = ((const float4*)gamma)[c4];
            const float4 bb = ((const float4*)beta)[c4];
            const float y0 = (v[i].x - mu) * rs * g.x + bb.x;
            const float y1 = (v[i].y - mu) * rs * g.y + bb.y;
            const float y2 = (v[i].z - mu) * rs * g.z + bb.z;
            const float y3 = (v[i].w - mu) * rs * g.w + bb.w;
            *(uint32_t*)&Alds[row * LDS_STRIDE + c4 * 4] = pack4_e4m3(y0, y1, y2, y3);
        }
    }
    __syncthreads();

    const int nl = lane & 15, quad = lane >> 4;
    f32x4 acc[MFRAG][NFRAG];
#pragma unroll
    for (int mf = 0; mf < MFRAG; ++mf)
#pragma unroll
        for (int f = 0; f < NFRAG; ++f) acc[mf][f] = (f32x4){0.f, 0.f, 0.f, 0.f};

    const uint8_t* ap[MFRAG];
#pragma unroll
    for (int mf = 0; mf < MFRAG; ++mf)
        ap[mf] = &Alds[(mf * 16 + nl) * LDS_STRIDE + quad * 8];

    const i64* Bq = (const i64*)Bp;
    const int fn0 = ny * 24 + wave * NFRAG;

    i64 bcur[NFRAG];
#pragma unroll
    for (int f = 0; f < NFRAG; ++f)
        bcur[f] = Bq[(size_t)((fn0 + f) * KK_STEPS) * 64 + lane];

#pragma unroll 4
    for (int kk = 0; kk < KK_STEPS; ++kk) {
        const int kn = (kk + 1 < KK_STEPS) ? kk + 1 : kk;
        i64 bnxt[NFRAG];
#pragma unroll
        for (int f = 0; f < NFRAG; ++f)
            bnxt[f] = Bq[(size_t)((fn0 + f) * KK_STEPS + kn) * 64 + lane];

        i64 a[MFRAG];
#pragma unroll
        for (int mf = 0; mf < MFRAG; ++mf)
            a[mf] = *(const i64*)(ap[mf] + kk * 32);

#pragma unroll
        for (int f = 0; f < NFRAG; ++f)
#pragma unroll
            for (int mf = 0; mf < MFRAG; ++mf)
                acc[mf][f] = __builtin_amdgcn_mfma_f32_16x16x32_fp8_fp8(a[mf], bcur[f], acc[mf][f], 0, 0, 0);

#pragma unroll
        for (int f = 0; f < NFRAG; ++f) bcur[f] = bnxt[f];
    }

#pragma unroll
    for (int f = 0; f < NFRAG; ++f) {
        const int col = ny * BN + wave * 96 + f * 16 + nl;
        const float bv = bias[col];
#pragma unroll
        for (int mf = 0; mf < MFRAG; ++mf) {
            const int row = row0 + mf * 16 + quad * 4;
            float* o = out + (size_t)row * UNITS + col;
            o[0 * UNITS] = acc[mf][f][0] + bv;
            o[1 * UNITS] = acc[mf][f][1] + bv;
            o[2 * UNITS] = acc[mf][f][2] + bv;
            o[3 * UNITS] = acc[mf][f][3] + bv;
        }
    }
}

extern "C" void kernel_launch(void* const* d_in, const int* in_sizes, int n_in,
                              void* d_out, int out_size, void* d_ws, size_t ws_size,
                              hipStream_t stream) {
    const float* x     = (const float*)d_in[0];
    const float* gamma = (const float*)d_in[1];
    const float* beta  = (const float*)d_in[2];
    const float* kern  = (const float*)d_in[3];
    const float* bias  = (const float*)d_in[4];
    float* out = (float*)d_out;
    const int tokens = in_sizes[0] / HID;

    uint8_t* Bp = (uint8_t*)d_ws;                    // 48*24*512 = 589824 B
    const size_t bp_bytes = (size_t)NPKT * 512;
    const size_t ap_bytes = (size_t)tokens * HID;    // fp8 activations, 50.3 MB

    hipLaunchKernelGGL(pack_b_kernel, dim3((NPKT * 64 + 255) / 256), dim3(256), 0, stream,
                       kern, Bp);

    if (ws_size >= bp_bytes + ap_bytes) {
        uint8_t* Ap = Bp + bp_bytes;
        hipLaunchKernelGGL(ln_pack_a, dim3(tokens / 16), dim3(256), 0, stream,
                           x, gamma, beta, Ap);
        hipLaunchKernelGGL(gemm_packed, dim3((tokens / BM) * 2), dim3(256), 0, stream,
                           Ap, Bp, bias, out);
    } else {
        // workspace too small for the split path: previous proven fused kernel
        hipLaunchKernelGGL(fused_ln_gemm, dim3((tokens / BM) * 2), dim3(256), 0, stream,
                           x, gamma, beta, Bp, bias, out);
    }
}

// Round 3
// 385.732 us; speedup vs baseline: 1.0824x; 1.0707x over previous
//
#include <hip/hip_runtime.h>
#include <stdint.h>

typedef float f32x4 __attribute__((ext_vector_type(4)));
typedef long i64;

#define HID 768
#define UNITS 768
#define BM 64               /* rows per block */
#define BN 384              /* cols per n-half */
#define LDS_STRIDE 776      /* 768 + 8 pad: <=2-way LDS aliasing on ds_read_b64 (0 conflicts measured) */
#define NFRAG 6             /* n-frags per wave: 6*16 = 96 cols */
#define MFRAG 4             /* m-frags per wave: 4*16 = 64 rows */
#define KK_STEPS 24         /* 768 / 32 */
#define NPKT (48 * 24)      /* B n-frag tiles * k-steps */

// ---------- fp8 e4m3fn conversion (RNE, saturating) ----------
__device__ __forceinline__ uint8_t f32_to_e4m3_sw(float x) {
    uint32_t u;
    __builtin_memcpy(&u, &x, 4);
    uint32_t sign = (u >> 24) & 0x80u;
    uint32_t a = u & 0x7fffffffu;
    if (a > 0x43e00000u) return (uint8_t)(sign | 0x7e);      // >448: saturate
    if (a < 0x3c800000u) {                                   // < 2^-6: subnormal
        float s;
        __builtin_memcpy(&s, &a, 4);
        int q = (int)rintf(s * 512.0f);
        return (uint8_t)(sign | (uint32_t)q);
    }
    uint32_t e = a >> 23;
    uint32_t m = a & 0x7fffffu;
    uint32_t mant = m >> 20;
    uint32_t rest = m & 0xfffffu;
    mant += (rest > 0x80000u) || (rest == 0x80000u && (mant & 1u));
    uint32_t te = e - 127u + 7u;
    if (mant == 8u) { mant = 0u; te += 1u; }
    return (uint8_t)(sign | (te << 3) | mant);
}

__device__ __forceinline__ uint32_t pack4_e4m3(float a, float b, float c, float d) {
#if __has_builtin(__builtin_amdgcn_cvt_pk_fp8_f32)
    int v = 0;
    v = __builtin_amdgcn_cvt_pk_fp8_f32(a, b, v, false);     // bytes 0,1
    v = __builtin_amdgcn_cvt_pk_fp8_f32(c, d, v, true);      // bytes 2,3
    return (uint32_t)v;
#else
    return (uint32_t)f32_to_e4m3_sw(a) | ((uint32_t)f32_to_e4m3_sw(b) << 8) |
           ((uint32_t)f32_to_e4m3_sw(c) << 16) | ((uint32_t)f32_to_e4m3_sw(d) << 24);
#endif
}

// ---------- kernel 1: quantize + frag-pack weights ----------
// Packet p = fn*KK_STEPS + kk. Byte offset p*512 + lane*8 holds
// B[k][n] for n = fn*16 + (lane&15), k = kk*32 + (lane>>4)*8 + j  (j = byte 0..7)
__global__ void pack_b_kernel(const float* __restrict__ K, uint8_t* __restrict__ Bp) {
    const int lane = threadIdx.x & 63;
    const int wid = (int)((blockIdx.x * blockDim.x + threadIdx.x) >> 6);
    if (wid >= NPKT) return;
    const int fn = wid / KK_STEPS, kk = wid % KK_STEPS;
    const int n = fn * 16 + (lane & 15);
    const int k0 = kk * 32 + (lane >> 4) * 8;
    float v[8];
#pragma unroll
    for (int j = 0; j < 8; ++j) v[j] = K[(size_t)(k0 + j) * UNITS + n];
    uint2 pr;
    pr.x = pack4_e4m3(v[0], v[1], v[2], v[3]);
    pr.y = pack4_e4m3(v[4], v[5], v[6], v[7]);
    *(uint2*)(Bp + ((size_t)wid << 9) + (size_t)lane * 8) = pr;
}

// ---------- kernel 2: fused LN(once) + fp8 quantize + GEMM(both n-halves) + bias ----------
// One block per 64-row m-tile. LN each row exactly once (round-0 did it twice,
// once per n-half). Phase B loops ny=0,1 reusing the LDS A-tile.
// 2 blocks/CU resident (49.6 KB LDS, <=256 VGPR) -> LN of one block overlaps
// GEMM of the other; setprio biases the scheduler toward MFMA waves (T5:
// applicable because resident waves are in different phases).
__global__ __launch_bounds__(256, 2)
void fused_ln_gemm_v2(const float* __restrict__ x,
                      const float* __restrict__ gamma,
                      const float* __restrict__ beta,
                      const uint8_t* __restrict__ Bp,
                      const float* __restrict__ bias,
                      float* __restrict__ out) {
    __shared__ uint8_t Alds[BM * LDS_STRIDE];
    const int tid = threadIdx.x;
    const int lane = tid & 63;
    const int wave = tid >> 6;
    const int mt = (int)blockIdx.x;
    const int row0 = mt * BM;

    // ---- Phase A: LayerNorm + quantize, 16 rows/wave in 4 batches of 4 ----
    float4 g[3], bbv[3];
#pragma unroll
    for (int i = 0; i < 3; ++i) {
        g[i]   = ((const float4*)gamma)[i * 64 + lane];
        bbv[i] = ((const float4*)beta )[i * 64 + lane];
    }
#pragma unroll
    for (int b = 0; b < 4; ++b) {
        const int lrow0 = wave * 16 + b * 4;      // LDS row of first of the 4
        float4 v[4][3];
        float s[4], s2[4];
#pragma unroll
        for (int r = 0; r < 4; ++r) {             // 12 loads in flight
            const float4* xr = (const float4*)(x + (size_t)(row0 + lrow0 + r) * HID);
            s[r] = 0.f; s2[r] = 0.f;
#pragma unroll
            for (int i = 0; i < 3; ++i) {
                const float4 t = xr[i * 64 + lane];
                v[r][i] = t;
                s[r]  += t.x + t.y + t.z + t.w;
                s2[r] += t.x * t.x + t.y * t.y + t.z * t.z + t.w * t.w;
            }
        }
#pragma unroll
        for (int off = 32; off; off >>= 1) {      // 4 interleaved butterfly chains
#pragma unroll
            for (int r = 0; r < 4; ++r) {
                s[r]  += __shfl_xor(s[r], off);
                s2[r] += __shfl_xor(s2[r], off);
            }
        }
#pragma unroll
        for (int r = 0; r < 4; ++r) {
            const float mu = s[r] * (1.0f / HID);
            const float var = fmaxf(s2[r] * (1.0f / HID) - mu * mu, 0.0f);
            const float rs = rsqrtf(var + 1e-5f);
#pragma unroll
            for (int i = 0; i < 3; ++i) {
                const int c4 = i * 64 + lane;
                const float y0 = (v[r][i].x - mu) * rs * g[i].x + bbv[i].x;
                const float y1 = (v[r][i].y - mu) * rs * g[i].y + bbv[i].y;
                const float y2 = (v[r][i].z - mu) * rs * g[i].z + bbv[i].z;
                const float y3 = (v[r][i].w - mu) * rs * g[i].w + bbv[i].w;
                *(uint32_t*)&Alds[(lrow0 + r) * LDS_STRIDE + c4 * 4] =
                    pack4_e4m3(y0, y1, y2, y3);
            }
        }
    }
    __syncthreads();

    // ---- Phase B: fp8 MFMA GEMM over both n-halves, A-tile reused from LDS ----
    const int nl = lane & 15, quad = lane >> 4;
    const uint8_t* ap[MFRAG];
#pragma unroll
    for (int mf = 0; mf < MFRAG; ++mf)
        ap[mf] = &Alds[(mf * 16 + nl) * LDS_STRIDE + quad * 8];
    const i64* Bq = (const i64*)Bp;

    for (int ny = 0; ny < 2; ++ny) {
        f32x4 acc[MFRAG][NFRAG];
#pragma unroll
        for (int mf = 0; mf < MFRAG; ++mf)
#pragma unroll
            for (int f = 0; f < NFRAG; ++f) acc[mf][f] = (f32x4){0.f, 0.f, 0.f, 0.f};

        const int fn0 = ny * 24 + wave * NFRAG;

        i64 bcur[NFRAG];
#pragma unroll
        for (int f = 0; f < NFRAG; ++f)
            bcur[f] = Bq[(size_t)((fn0 + f) * KK_STEPS) * 64 + lane];

#pragma unroll 4
        for (int kk = 0; kk < KK_STEPS; ++kk) {
            const int kn = (kk + 1 < KK_STEPS) ? kk + 1 : kk;
            i64 bnxt[NFRAG];
#pragma unroll
            for (int f = 0; f < NFRAG; ++f)
                bnxt[f] = Bq[(size_t)((fn0 + f) * KK_STEPS + kn) * 64 + lane];

            i64 a[MFRAG];
#pragma unroll
            for (int mf = 0; mf < MFRAG; ++mf)
                a[mf] = *(const i64*)(ap[mf] + kk * 32);

            __builtin_amdgcn_s_setprio(1);
#pragma unroll
            for (int f = 0; f < NFRAG; ++f)
#pragma unroll
                for (int mf = 0; mf < MFRAG; ++mf)
                    acc[mf][f] = __builtin_amdgcn_mfma_f32_16x16x32_fp8_fp8(
                        a[mf], bcur[f], acc[mf][f], 0, 0, 0);
            __builtin_amdgcn_s_setprio(0);

#pragma unroll
            for (int f = 0; f < NFRAG; ++f) bcur[f] = bnxt[f];
        }

        // ---- Epilogue: + bias, nontemporal fp32 stores (keep B L2-resident) ----
#pragma unroll
        for (int f = 0; f < NFRAG; ++f) {
            const int col = ny * BN + wave * 96 + f * 16 + nl;
            const float bv = bias[col];
#pragma unroll
            for (int mf = 0; mf < MFRAG; ++mf) {
                const int row = row0 + mf * 16 + quad * 4;
                float* o = out + (size_t)row * UNITS + col;
                __builtin_nontemporal_store(acc[mf][f][0] + bv, o + 0 * UNITS);
                __builtin_nontemporal_store(acc[mf][f][1] + bv, o + 1 * UNITS);
                __builtin_nontemporal_store(acc[mf][f][2] + bv, o + 2 * UNITS);
                __builtin_nontemporal_store(acc[mf][f][3] + bv, o + 3 * UNITS);
            }
        }
    }
}

extern "C" void kernel_launch(void* const* d_in, const int* in_sizes, int n_in,
                              void* d_out, int out_size, void* d_ws, size_t ws_size,
                              hipStream_t stream) {
    const float* x     = (const float*)d_in[0];
    const float* gamma = (const float*)d_in[1];
    const float* beta  = (const float*)d_in[2];
    const float* kern  = (const float*)d_in[3];
    const float* bias  = (const float*)d_in[4];
    float* out = (float*)d_out;
    uint8_t* Bp = (uint8_t*)d_ws;   // needs 48*24*512 = 589824 bytes
    const int tokens = in_sizes[0] / HID;

    hipLaunchKernelGGL(pack_b_kernel, dim3((NPKT * 64 + 255) / 256), dim3(256), 0, stream,
                       kern, Bp);
    hipLaunchKernelGGL(fused_ln_gemm_v2, dim3(tokens / BM), dim3(256), 0, stream,
                       x, gamma, beta, Bp, bias, out);
}